// Round 9
// baseline (150.771 us; speedup 1.0000x reference)
//
#include <hip/hip_runtime.h>
#include <cstdint>
#include <cstddef>

typedef unsigned long long ull;
typedef __bf16 bf16x8 __attribute__((ext_vector_type(8)));
typedef float f32x4 __attribute__((ext_vector_type(4)));

#define NA     147456   // 128*128*9 anchors
#define NT     64       // targets
#define KDIM   4608     // 512*9 reduction
#define NTASK  1280     // 128*6 + 256*2 output-value tasks
#define CAND_CAP 4096
#define KSPLIT 8
#define NSTEP  18       // 72 kc per split / 4 kc per MFMA step
#define NIOUB  576      // iou blocks
#define NTRB   2048     // transpose blocks
#define NPREP2 512      // weight-prep blocks (one per cout row)
#define NZERO  197      // zero-fill blocks: 17408 (zero page) + 33024 (halo) uint4 stores

// ---- workspace byte offsets (~45.1 MB) ----
#define OFF_WB2   0           // ushort[576*512*8]  bf16 weights, frag-native [kc][m][8]
#define OFF_XT    4718592     // ushort[130*130*512] bf16 NHWC x, 1-pixel zero halo (17.3 MB)
#define OFF_ZERO  22024192    // ushort zero page, 278528 B (invalid-task B gather target)
#define OFF_H4    22302720    // float[KSPLIT][1280][512] K-split partial h (20.97 MB)
#define OFF_MIOU  43274240    // float[147456]
#define OFF_CAND  43864064    // ull[576*256]
#define OFF_CPB   45043712    // int[576]
#define OFF_CBZ   45046016    // int[576]
#define OFF_NPOS  45048320    // int
#define OFF_TREG  45048336    // float[512]
#define OFF_TASKS 45050384    // int[1280]

// anchor w/h table; U = sqrt(128*128/2); power-of-2 multiples are exact in fp32.
#define UANC 90.509667991878f
__device__ __constant__ float WKa[9] = {128.0f, 2.0f*UANC, UANC, 256.0f, 4.0f*UANC, 2.0f*UANC, 512.0f, 8.0f*UANC, 4.0f*UANC};
__device__ __constant__ float HKa[9] = {128.0f, UANC, 2.0f*UANC, 256.0f, 2.0f*UANC, 4.0f*UANC, 512.0f, 4.0f*UANC, 8.0f*UANC};

__device__ __forceinline__ float iou_one(float x1, float y1, float x2, float y2, float4 t) {
#pragma clang fp contract(off)
  float ltx = fmaxf(t.x, x1), lty = fmaxf(t.y, y1);
  float rbx = fminf(t.z, x2), rby = fminf(t.w, y2);
  float wx = fmaxf(rbx - ltx, 0.0f);
  float wy = fmaxf(rby - lty, 0.0f);
  float inter = wx * wy;
  float at = (t.z - t.x) * (t.w - t.y);
  float aa = (x2 - x1) * (y2 - y1);
  return inter / ((at + aa) - inter);
}

__device__ __forceinline__ unsigned short f2bf(float f) {
  unsigned int u = __float_as_uint(f);
  unsigned int r = (u + 0x7fffu + ((u >> 16) & 1u)) >> 16;
  return (unsigned short)r;
}

// B-gather K-step offset (shorts): kcb in [0,576), 4-aligned, quad never carries into kc>>6
__device__ __forceinline__ int boff(int kcb) {
  int rk = kcb >> 6;                 // 0..8
  int dy = (rk * 11) >> 5;           // rk/3 for rk in [0,8]
  int dxo = rk - dy * 3;
  return (dy * 130 + dxo) * 512 + (kcb & 63) * 8;
}

// four-role kernel, all selection-independent work:
//   [0,576):      IoU + per-block candidate/zero stats
//   [576,2624):   x NCHW fp32 -> padded NHWC bf16 transpose (64x64 LDS tile)
//   [2624,3136):  weight repack, LDS-staged
//   [3136,3333):  zero page + halo zero-fill + out[0]=0
__global__ __launch_bounds__(256) void k_pi(const float* __restrict__ cw,
    unsigned short* __restrict__ Wb2, const float* __restrict__ x,
    unsigned short* __restrict__ xtb, unsigned short* __restrict__ zrg,
    const float* __restrict__ tgt, const int* __restrict__ imw,
    const int* __restrict__ imh, float* __restrict__ miou,
    ull* __restrict__ cand, int* __restrict__ cpb, int* __restrict__ cbz,
    float* __restrict__ out0) {
  __shared__ __align__(16) char smem[20480];
  int blk = blockIdx.x;
  int tid = threadIdx.x;
  if (blk >= NIOUB + NTRB + NPREP2) {          // ---- zero page + halo ----
    int g = (blk - (NIOUB + NTRB + NPREP2)) * 256 + tid;   // [0, 50432)
    uint4 z = {0u, 0u, 0u, 0u};
    if (g == 0) *out0 = 0.0f;                  // loss accumulator init
    if (g < 17408) {
      *(uint4*)(zrg + g * 8) = z;
    } else {
      int h = g - 17408;
      int pixi = h >> 6, j = h & 63;           // 516 halo pixels x 64 uint4
      int yy, xx;
      if (pixi < 260) { yy = (pixi < 130) ? 0 : 129; xx = (pixi < 130) ? pixi : pixi - 130; }
      else { int p2 = pixi - 260; if (p2 < 128) { yy = 1 + p2; xx = 0; } else { yy = p2 - 127; xx = 129; } }
      *(uint4*)(xtb + (size_t)(yy * 130 + xx) * 512 + j * 8) = z;
    }
    return;
  }
  if (blk >= NIOUB + NTRB) {                   // ---- prep: one cout row, LDS-staged ----
    float* row = (float*)smem;                 // padded [cin*10 + r]
    int m = blk - (NIOUB + NTRB);
    const float* src = cw + (size_t)m * KDIM;
    for (int f = tid; f < KDIM; f += 256) {
      int cin = f / 9;
      row[cin * 10 + (f - cin * 9)] = src[f];
    }
    __syncthreads();
    for (int kc = tid; kc < 576; kc += 256) {
      int r = kc >> 6, c8 = kc & 63;
      int base = c8 * 80 + r;
      unsigned short o[8];
      #pragma unroll
      for (int j = 0; j < 8; ++j) o[j] = f2bf(row[base + j * 10]);
      *(uint4*)(Wb2 + ((size_t)kc * 512 + m) * 8) = *(const uint4*)o;
    }
    return;
  }
  if (blk >= NIOUB) {                          // ---- transpose 64pix x 64cin, padded bf16 out ----
    float* tile = (float*)smem;                // [64][65]
    int tb = blk - NIOUB;
    int pix0 = (tb & 255) * 64;
    int cin0 = (tb >> 8) * 64;
    int pr = tid & 15, cr = tid >> 4;
    #pragma unroll
    for (int i = 0; i < 4; ++i) {
      int cin = cr + i * 16;
      float4 v = *(const float4*)(x + (size_t)(cin0 + cin) * 16384 + pix0 + pr * 4);
      tile[cin * 65 + pr * 4 + 0] = v.x;
      tile[cin * 65 + pr * 4 + 1] = v.y;
      tile[cin * 65 + pr * 4 + 2] = v.z;
      tile[cin * 65 + pr * 4 + 3] = v.w;
    }
    __syncthreads();
    // write: 16B stores, 8 bf16 along cin per lane; bank = (8*pr8+pix+j)%32 -> 2-way (free)
    int pr8 = tid & 7, cr8 = tid >> 3;         // 8 cin-groups x 32 pix rows
    #pragma unroll
    for (int pass = 0; pass < 2; ++pass) {
      int pix = cr8 + pass * 32;
      int plin = pix0 + pix;
      int py = plin >> 7, px = plin & 127;
      unsigned short o[8];
      #pragma unroll
      for (int j = 0; j < 8; ++j) o[j] = f2bf(tile[(pr8 * 8 + j) * 65 + pix]);
      *(uint4*)(xtb + (size_t)((py + 1) * 130 + (px + 1)) * 512 + cin0 + pr8 * 8) = *(const uint4*)o;
    }
    return;
  }
  // ---- IoU ----
  float4* ts = (float4*)smem;                  // [64]
  int* wz = (int*)(smem + 1024);
  int* wc = wz + 4;
  if (tid < NT) ts[tid] = ((const float4*)tgt)[tid];
  __syncthreads();
  int a = blk * 256 + tid;
  int k = a % 9;
  int pq = a / 9;
  int p = pq >> 7, q = pq & 127;
  float dx = (float)(*imw) / 127.0f;
  float dyl = (float)(*imh) / 127.0f;
  float x1 = (float)p * dx, y1 = (float)q * dyl;
  float x2 = x1 + WKa[k], y2 = y1 + HKa[k];
  float best = -1.0f;
  #pragma unroll 8
  for (int t = 0; t < NT; ++t) best = fmaxf(best, iou_one(x1, y1, x2, y2, ts[t]));
  miou[a] = best;
  int lane = tid & 63, w = tid >> 6;
  ull bz = __ballot(best == 0.0f);
  bool isc = best > 0.7f;
  ull bc = __ballot(isc);
  if (lane == 0) { wz[w] = (int)__popcll(bz); wc[w] = (int)__popcll(bc); }
  __syncthreads();
  if (tid == 0) {
    cbz[blk] = wz[0] + wz[1] + wz[2] + wz[3];
    cpb[blk] = wc[0] + wc[1] + wc[2] + wc[3];
  }
  if (isc) {
    int woff = 0;
    for (int i = 0; i < w; ++i) woff += wc[i];
    int rank = woff + (int)__popcll(bc & ((1ull << lane) - 1ull));
    cand[blk * 256 + rank] = ((ull)__float_as_uint(best) << 32) | (ull)(0xFFFFFFFFu - (unsigned)a);
  }
}

// two concurrent blocks:
//   block 0: pos-select (radix top-128 SET) + treg + pos task table [0,768)
//   block 1: neg-select + neg task table [768,1280) (recs unconditional;
//            np-validity is applied in k_out, which reads nposp anyway)
__global__ __launch_bounds__(256) void k_sel(const ull* __restrict__ cand,
    const int* __restrict__ cpb, const float* __restrict__ miou,
    const int* __restrict__ cbz, const float* __restrict__ tgt,
    const int* __restrict__ imw, const int* __restrict__ imh,
    int* __restrict__ nposp, float* __restrict__ treg, int* __restrict__ tasks) {
  __shared__ ull keys[CAND_CAP];               // 32 KB
  __shared__ ull bnd[1024];                    // 8 KB
  __shared__ int hist[1024];                   // 4 KB
  __shared__ int cpbL[576];
  __shared__ int base576[577];
  __shared__ int wtot[4];
  __shared__ int selCnt, bndCnt, Tbin, mAbove;
  __shared__ int posi[128];
  __shared__ int npS;
  __shared__ int nzbase[145];
  __shared__ float4 ts[NT];
  __shared__ int negA[256];
  __shared__ int wsum[4];
  int tid = threadIdx.x;
  int lane = tid & 63;

  if (blockIdx.x == 1) {                       // ======== neg path ========
    int sB = 0, scanB = 0;
    if (tid < 144) {
      int4 cz4 = *(const int4*)(cbz + 4 * tid);
      sB = cz4.x + cz4.y + cz4.z + cz4.w;
      scanB = sB;
      for (int off = 1; off < 64; off <<= 1) {
        int v = __shfl_up(scanB, off);
        if (lane >= off) scanB += v;
      }
      bool last = (tid < 128) ? (lane == 63) : (tid == 143);
      if (last) wsum[tid >> 6] = scanB;
    }
    __syncthreads();
    if (tid < 144) {
      int w = tid >> 6;
      int woff = 0;
      for (int i = 0; i < w; ++i) woff += wsum[i];
      nzbase[tid] = woff + scanB - sB;
      if (tid == 143) nzbase[144] = woff + scanB;
    }
    __syncthreads();
    int w = tid >> 6;
    for (int j = 0; j < 144; ++j) {
      if (nzbase[j] >= 256) break;             // uniform
      int a0 = j * 1024 + tid * 4;
      float4 m4 = *(const float4*)(miou + a0);
      int f0 = (m4.x == 0.0f), f1 = (m4.y == 0.0f), f2 = (m4.z == 0.0f), f3 = (m4.w == 0.0f);
      int tsum = f0 + f1 + f2 + f3;
      int scan = tsum;
      for (int off = 1; off < 64; off <<= 1) {
        int v = __shfl_up(scan, off);
        if (lane >= off) scan += v;
      }
      if (lane == 63) wsum[w] = scan;
      __syncthreads();
      int woff = nzbase[j];
      for (int i = 0; i < w; ++i) woff += wsum[i];
      int r = woff + scan - tsum;
      if (f0) { if (r < 256) negA[r] = a0;     r++; }
      if (f1) { if (r < 256) negA[r] = a0 + 1; r++; }
      if (f2) { if (r < 256) negA[r] = a0 + 2; r++; }
      if (f3) { if (r < 256) negA[r] = a0 + 3;      }
      __syncthreads();
    }
    __syncthreads();
    for (int t = 768 + tid; t < NTASK; t += 256) {
      int s = (t - 768) >> 1, jj = (t - 768) & 1;
      int a = negA[s];
      int f = 2 * a; int wr = 36 + (f >> 14); int yy = (f >> 7) & 127; int xx = (f & 127) + jj;
      tasks[t] = (int)(0x80000000u | ((unsigned)wr << 16) | ((unsigned)yy << 8) | (unsigned)xx);
    }
    return;
  }

  // ======== pos path (block 0) ========
  if (tid < NT) ts[tid] = ((const float4*)tgt)[tid];
  for (int i = tid; i < 576; i += 256) cpbL[i] = cpb[i];
  for (int i = tid; i < 1024; i += 256) hist[i] = 0;
  __syncthreads();
  int e0 = 0, e1 = 0, sA = 0, scanA = 0;
  if (tid < 192) {
    e0 = cpbL[3 * tid]; e1 = cpbL[3 * tid + 1]; int e2 = cpbL[3 * tid + 2];
    sA = e0 + e1 + e2;
    scanA = sA;
    for (int off = 1; off < 64; off <<= 1) {
      int v = __shfl_up(scanA, off);
      if (lane >= off) scanA += v;
    }
    if (lane == 63) wtot[tid >> 6] = scanA;
  }
  __syncthreads();
  if (tid < 192) {
    int w = tid >> 6;
    int woff = 0;
    for (int i = 0; i < w; ++i) woff += wtot[i];
    int excl = woff + scanA - sA;
    base576[3 * tid]     = excl;
    base576[3 * tid + 1] = excl + e0;
    base576[3 * tid + 2] = excl + e0 + e1;
    if (tid == 191) base576[576] = excl + sA;
  }
  __syncthreads();
  int cnt = base576[576]; if (cnt > CAND_CAP) cnt = CAND_CAP;
  for (int i = tid; i < CAND_CAP; i += 256) if (i >= cnt) keys[i] = 0ull;
  for (int rk = tid; rk < cnt; rk += 256) {
    int lo = 0, hi = 576;
    while (hi - lo > 1) { int mid = (lo + hi) >> 1; if (base576[mid] <= rk) lo = mid; else hi = mid; }
    keys[rk] = cand[lo * 256 + (rk - base576[lo])];
  }
  __syncthreads();
  if (cnt <= 128) {                            // set-invariant: slot order irrelevant
    if (tid < cnt) posi[tid] = (int)(0xFFFFFFFFu - (unsigned)(keys[tid] & 0xFFFFFFFFull));
    if (tid == 0) { npS = cnt; *nposp = cnt; }
  } else {
    for (int i = tid; i < cnt; i += 256) {
      unsigned ib = (unsigned)(keys[i] >> 32);
      atomicAdd(&hist[(ib - 0x3F333334u) >> 13], 1);
    }
    __syncthreads();
    if (tid < 64) {
      int s = 0;
      #pragma unroll
      for (int t = 0; t < 16; ++t) s += hist[tid * 16 + t];
      int S = s;
      #pragma unroll
      for (int off = 1; off < 64; off <<= 1) {
        int u = __shfl_down(S, off);
        if (tid + off < 64) S += u;
      }
      ull mask = __ballot(S >= 128);
      int g = 63 - __clzll(mask);
      int aboveS = __shfl(S, (g + 1 < 64) ? g + 1 : 63);
      if (g == 63) aboveS = 0;
      if (tid == 0) {
        int run = aboveS, T = g * 16 + 15;
        for (int b = g * 16 + 15; b >= g * 16; --b) {
          int h = hist[b];
          if (run + h >= 128) { T = b; break; }
          run += h;
        }
        Tbin = T; mAbove = run; selCnt = 0; bndCnt = 0;
      }
    }
    __syncthreads();
    int T = Tbin, m = mAbove;
    for (int i = tid; i < cnt; i += 256) {
      ull kk = keys[i];
      unsigned ib = (unsigned)(kk >> 32);
      int b = (int)((ib - 0x3F333334u) >> 13);
      if (b > T) {
        int r = atomicAdd(&selCnt, 1);
        posi[r] = (int)(0xFFFFFFFFu - (unsigned)(kk & 0xFFFFFFFFull));
      } else if (b == T) {
        int r = atomicAdd(&bndCnt, 1);
        if (r < 1024) bnd[r] = kk;
      }
    }
    __syncthreads();
    int B = bndCnt;
    int need = 128 - m;
    if (B <= 1024) {
      int n2 = 2; while (n2 < B) n2 <<= 1;
      for (int i = tid; i < n2; i += 256) if (i >= B) bnd[i] = 0ull;
      for (int size = 2; size <= n2; size <<= 1)
        for (int stride = size >> 1; stride > 0; stride >>= 1) {
          __syncthreads();
          for (int t = tid; t < n2 / 2; t += 256) {
            int i = 2 * t - (t & (stride - 1));
            int j = i + stride;
            ull a = bnd[i], b2 = bnd[j];
            bool desc = ((i & size) == 0);
            if (desc ? (a < b2) : (a > b2)) { bnd[i] = b2; bnd[j] = a; }
          }
        }
      __syncthreads();
      if (tid < need) posi[m + tid] = (int)(0xFFFFFFFFu - (unsigned)(bnd[tid] & 0xFFFFFFFFull));
    } else {                                   // pathological tie storm: full sort fallback
      for (int size = 2; size <= CAND_CAP; size <<= 1)
        for (int stride = size >> 1; stride > 0; stride >>= 1) {
          __syncthreads();
          for (int t = tid; t < CAND_CAP / 2; t += 256) {
            int i = 2 * t - (t & (stride - 1));
            int j = i + stride;
            ull a = keys[i], b2 = keys[j];
            bool desc = ((i & size) == 0);
            if (desc ? (a < b2) : (a > b2)) { keys[i] = b2; keys[j] = a; }
          }
        }
      __syncthreads();
      if (tid < 128) posi[tid] = (int)(0xFFFFFFFFu - (unsigned)(keys[tid] & 0xFFFFFFFFull));
    }
    if (tid == 0) { npS = 128; *nposp = 128; }
  }
  __syncthreads();
  int np = npS;
  if (tid < np) {
    int a = posi[tid];
    int k = a % 9; int pq = a / 9; int p = pq >> 7, q = pq & 127;
    float dx = (float)(*imw) / 127.0f, dyl = (float)(*imh) / 127.0f;
    float x1 = (float)p * dx, y1 = (float)q * dyl;
    float x2 = x1 + WKa[k], y2 = y1 + HKa[k];
    float best = -1.0f; int bt = 0;
    for (int t = 0; t < NT; ++t) {
      float v = iou_one(x1, y1, x2, y2, ts[t]);
      if (v > best) { best = v; bt = t; }      // first-max == jnp.argmax
    }
    float4 m = ts[bt];
    float aw = x2 - x1, ah = y2 - y1;
    float acx = x1 + aw * 0.5f, acy = y1 + ah * 0.5f;
    float bwd = m.z - m.x, bhd = m.w - m.y;
    float bcx = m.x + bwd * 0.5f, bcy = m.y + bhd * 0.5f;
    treg[tid * 4 + 0] = (bcx - acx) / aw;
    treg[tid * 4 + 1] = (bcy - acy) / ah;
    treg[tid * 4 + 2] = logf(bwd / aw);
    treg[tid * 4 + 3] = logf(bhd / ah);
  }
  for (int t = tid; t < 768; t += 256) {
    int rec = 0;
    int s = t / 6, jj = t - s * 6;
    if (s < np) {
      int a = posi[s];
      int f, wr, xx;
      if (jj < 4) { f = 4 * a; wr = f >> 14; xx = (f & 127) + jj; }
      else        { f = 2 * a; wr = 36 + (f >> 14); xx = (f & 127) + (jj - 4); }
      int yy = (f >> 7) & 127;
      rec = (int)(0x80000000u | ((unsigned)wr << 16) | ((unsigned)yy << 8) | (unsigned)xx);
    }
    tasks[t] = rec;
  }
}

// LDS-free-operand bf16 MFMA GEMM, im2col folded into the B-operand gather.
// 4-wave blocks: waves round-robin the 18 K-steps of one 64x64xKslice tile
// (disjoint 4-kc steps), then a 2-stage LDS reduction ((w0+w2)+(w1+w3)).
// Grid (20,8,8) x 4 waves = 5120 waves (~4/SIMD); H4 stays at 8 slices.
__global__ __launch_bounds__(256) void k_mfma(const unsigned short* __restrict__ Wb2,
    const unsigned short* __restrict__ xtb, const unsigned short* __restrict__ zrg,
    const int* __restrict__ tasks, const int* __restrict__ nposp,
    float* __restrict__ H4) {
  __shared__ __align__(16) float red[2][64][68];   // 2 x 17408 B (pad 68: 2-way banks)
  int npos = *nposp;
  int tt0 = blockIdx.x * 64;
  int posend = 6 * npos, negend = 768 + 2 * (256 - npos);
  if (!((tt0 < posend) || ((tt0 + 64 > 768) && (tt0 < negend)))) return;
  int m_base = blockIdx.y * 64;
  int ks = blockIdx.z;
  int tid = threadIdx.x;
  int wave = tid >> 6, lane = tid & 63;
  int quad = lane >> 4, r = lane & 15;
  const bf16x8* Ab = (const bf16x8*)Wb2 + ((size_t)(ks * 72 + quad) * 512 + m_base + r);

  // per-lane B gather base pointers (one task per (ni,r))
  const unsigned short* Bp[4];
  #pragma unroll
  for (int ni = 0; ni < 4; ++ni) {
    int rec = tasks[tt0 + ni * 16 + r];
    int pix = (rec < 0) ? (((rec >> 8) & 127) * 130 + (rec & 127)) : 0;
    const unsigned short* base = (rec < 0) ? xtb : zrg;
    Bp[ni] = base + (size_t)pix * 512 + quad * 8;
  }
  int kcb = ks * 72;

  f32x4 acc[4][4];
  #pragma unroll
  for (int i = 0; i < 4; ++i)
    #pragma unroll
    for (int j = 0; j < 4; ++j) acc[i][j] = (f32x4){0.f, 0.f, 0.f, 0.f};

  bf16x8 a[4], b[4];
  {
    const bf16x8* An = Ab + (size_t)(4 * wave) * 512;
    int ob = boff(kcb + 4 * wave);
    #pragma unroll
    for (int mi = 0; mi < 4; ++mi) a[mi] = An[mi * 16];
    #pragma unroll
    for (int ni = 0; ni < 4; ++ni) b[ni] = *(const bf16x8*)(Bp[ni] + ob);
  }
  for (int s = wave; s < NSTEP; s += 4) {
    bf16x8 an[4], bn[4];
    int sn = s + 4;
    if (sn < NSTEP) {
      const bf16x8* An = Ab + (size_t)(4 * sn) * 512;
      int ob = boff(kcb + 4 * sn);
      #pragma unroll
      for (int mi = 0; mi < 4; ++mi) an[mi] = An[mi * 16];
      #pragma unroll
      for (int ni = 0; ni < 4; ++ni) bn[ni] = *(const bf16x8*)(Bp[ni] + ob);
    }
    #pragma unroll
    for (int mi = 0; mi < 4; ++mi)
      #pragma unroll
      for (int ni = 0; ni < 4; ++ni)
        acc[mi][ni] = __builtin_amdgcn_mfma_f32_16x16x32_bf16(a[mi], b[ni], acc[mi][ni], 0, 0, 0);
    if (sn < NSTEP) {
      #pragma unroll
      for (int mi = 0; mi < 4; ++mi) a[mi] = an[mi];
      #pragma unroll
      for (int ni = 0; ni < 4; ++ni) b[ni] = bn[ni];
    }
  }

  // ---- in-block K reduction: final = (w0+w2) + (w1+w3), deterministic ----
  if (wave >= 2) {
    #pragma unroll
    for (int mi = 0; mi < 4; ++mi)
      #pragma unroll
      for (int ni = 0; ni < 4; ++ni)
        *(f32x4*)&red[wave - 2][ni * 16 + r][mi * 16 + quad * 4] = acc[mi][ni];
  }
  __syncthreads();
  if (wave < 2) {
    #pragma unroll
    for (int mi = 0; mi < 4; ++mi)
      #pragma unroll
      for (int ni = 0; ni < 4; ++ni)
        acc[mi][ni] += *(const f32x4*)&red[wave][ni * 16 + r][mi * 16 + quad * 4];
  }
  __syncthreads();
  if (wave == 1) {
    #pragma unroll
    for (int mi = 0; mi < 4; ++mi)
      #pragma unroll
      for (int ni = 0; ni < 4; ++ni)
        *(f32x4*)&red[0][ni * 16 + r][mi * 16 + quad * 4] = acc[mi][ni];
  }
  __syncthreads();
  if (wave == 0) {
    size_t hb = (size_t)ks * NTASK;
    #pragma unroll
    for (int mi = 0; mi < 4; ++mi) {
      int c = m_base + mi * 16 + quad * 4;
      #pragma unroll
      for (int ni = 0; ni < 4; ++ni) {
        acc[mi][ni] += *(const f32x4*)&red[0][ni * 16 + r][mi * 16 + quad * 4];
        int t = tt0 + ni * 16 + r;
        *(f32x4*)(H4 + (hb + t) * 512 + c) = acc[mi][ni];
      }
    }
  }
}

// epilogue + loss: 4 tasks per block (wave per task); each block atomicAdds its
// pre-scaled CE/reg contributions directly into out[0] (zeroed by k_pi).
// CE pairs (t0,t0+1) never cross a 4-task block: t0 mod 4 is always even.
// Neg-task validity (s < 256-np) is applied HERE (neg recs are unconditional).
__global__ __launch_bounds__(256) void k_out(const float* __restrict__ H4,
    const int* __restrict__ tasks,
    const float* __restrict__ cb, const float* __restrict__ bw,
    const float* __restrict__ bb, const float* __restrict__ sw,
    const float* __restrict__ sb, const float* __restrict__ treg,
    const int* __restrict__ nposp, float* __restrict__ out) {
  __shared__ float sOut[4];
  __shared__ float sContrib[4];
  int wave = threadIdx.x >> 6, lane = threadIdx.x & 63;
  int t = blockIdx.x * 4 + wave;
  int rec = tasks[t];
  int np = *nposp;
  float outval = 0.0f;
  if (rec < 0) {
    int wr = (rec >> 16) & 63;
    const float* wrow = (wr < 36) ? (bw + wr * 512) : (sw + (wr - 36) * 512);
    float s = 0.0f;
    #pragma unroll
    for (int it = 0; it < 8; ++it) {
      int c = it * 64 + lane;
      size_t o = (size_t)t * 512 + c;
      float hv = cb[c];
      #pragma unroll
      for (int kslice = 0; kslice < KSPLIT; ++kslice)
        hv += H4[o + (size_t)kslice * 1280 * 512];
      s = fmaf(fmaxf(hv, 0.0f), wrow[c], s);
    }
    #pragma unroll
    for (int off = 32; off > 0; off >>= 1) s += __shfl_down(s, off);
    if (lane == 0) {
      float b = (wr < 36) ? bb[wr] : sb[wr - 36];
      outval = fmaxf(s + b, 0.0f);
    }
  }
  if (lane == 0) sOut[wave] = outval;
  __syncthreads();
  if (lane == 0) {
    float contrib = 0.0f;
    if (rec < 0) {
      if (t < 768) {
        int s6 = t / 6, j = t - s6 * 6;
        if (j < 4) {                           // smooth-L1 reg term
          float d = outval - treg[s6 * 4 + j];
          float ad = fabsf(d);
          float sl1 = (ad < 1.0f) ? 0.5f * d * d : ad - 0.5f;
          contrib = 10.0f * sl1 / fmaxf(4.0f * (float)np, 1.0f);
        } else if (j == 4) {                   // pos CE (partner j==5 at wave+1)
          float s0 = outval, s1 = sOut[wave + 1];
          float mm = fmaxf(s0, s1);
          float lse = mm + logf(expf(s0 - mm) + expf(s1 - mm));
          contrib = (lse - s0) * (1.0f / 256.0f);
        }
      } else if (((t - 768) & 1) == 0 && ((t - 768) >> 1) < 256 - np) {  // neg CE, masked by np
        float s0 = outval, s1 = sOut[wave + 1];
        float mm = fmaxf(s0, s1);
        float lse = mm + logf(expf(s0 - mm) + expf(s1 - mm));
        contrib = (lse - s1) * (1.0f / 256.0f);
      }
    }
    sContrib[wave] = contrib;
  }
  __syncthreads();
  if (threadIdx.x == 0) {
    float c = sContrib[0] + sContrib[1] + sContrib[2] + sContrib[3];
    if (c != 0.0f) atomicAdd(out, c);
  }
}

extern "C" void kernel_launch(void* const* d_in, const int* in_sizes, int n_in,
                              void* d_out, int out_size, void* d_ws, size_t ws_size,
                              hipStream_t stream) {
  const float* x   = (const float*)d_in[0];
  const float* tgt = (const float*)d_in[1];
  const float* cw  = (const float*)d_in[2];
  const float* cb  = (const float*)d_in[3];
  const float* bw  = (const float*)d_in[4];
  const float* bb  = (const float*)d_in[5];
  const float* sw  = (const float*)d_in[6];
  const float* sb  = (const float*)d_in[7];
  const int* imh   = (const int*)d_in[8];
  const int* imw   = (const int*)d_in[9];

  char* ws = (char*)d_ws;
  unsigned short* Wb2 = (unsigned short*)(ws + OFF_WB2);
  unsigned short* xtb = (unsigned short*)(ws + OFF_XT);
  unsigned short* zrg = (unsigned short*)(ws + OFF_ZERO);
  float* H4    = (float*)(ws + OFF_H4);
  float* miou  = (float*)(ws + OFF_MIOU);
  ull*   cand  = (ull*)(ws + OFF_CAND);
  int*   cpb   = (int*)(ws + OFF_CPB);
  int*   cbz   = (int*)(ws + OFF_CBZ);
  int*   nposp = (int*)(ws + OFF_NPOS);
  float* treg  = (float*)(ws + OFF_TREG);
  int*   tasks = (int*)(ws + OFF_TASKS);
  float* out   = (float*)d_out;

  k_pi   <<<dim3(NIOUB + NTRB + NPREP2 + NZERO), dim3(256), 0, stream>>>(cw, Wb2, x, xtb, zrg, tgt, imw, imh, miou, cand, cpb, cbz, out);
  k_sel  <<<dim3(2),              dim3(256), 0, stream>>>(cand, cpb, miou, cbz, tgt, imw, imh, nposp, treg, tasks);
  k_mfma <<<dim3(20, 8, KSPLIT),  dim3(256), 0, stream>>>(Wb2, xtb, zrg, tasks, nposp, H4);
  k_out  <<<dim3(320),            dim3(256), 0, stream>>>(H4, tasks, cb, bw, bb, sw, sb, treg, nposp, out);
}

// Round 10
// 145.140 us; speedup vs baseline: 1.0388x; 1.0388x over previous
//
#include <hip/hip_runtime.h>
#include <cstdint>
#include <cstddef>

typedef unsigned long long ull;
typedef __bf16 bf16x8 __attribute__((ext_vector_type(8)));
typedef float f32x4 __attribute__((ext_vector_type(4)));

#define NA     147456   // 128*128*9 anchors
#define NT     64       // targets
#define KDIM   4608     // 512*9 reduction
#define NTASK  1280     // 128*6 + 256*2 output-value tasks
#define CAND_CAP 4096
#define KSPLIT 8
#define NSTEP  18       // 72 kc per split / 4 kc per MFMA step
#define NIOUB  576      // iou blocks
#define NTRB   2048     // transpose blocks
#define NPREP2 512      // weight-prep blocks (one per cout row)
#define NZERO  197      // zero-fill blocks: 17408 (zero page) + 33024 (halo) uint4 stores

// ---- workspace byte offsets (~45.1 MB) ----
#define OFF_WB2   0           // ushort[576*512*8]  bf16 weights, frag-native [kc][m][8]
#define OFF_XT    4718592     // ushort[130*130*512] bf16 NHWC x, 1-pixel zero halo (17.3 MB)
#define OFF_ZERO  22024192    // ushort zero page, 278528 B (invalid-task B gather target)
#define OFF_H4    22302720    // float[KSPLIT][1280][512] K-split partial h (20.97 MB)
#define OFF_MIOU  43274240    // float[147456]
#define OFF_CAND  43864064    // ull[576*256]
#define OFF_CPB   45043712    // int[576]
#define OFF_CBZ   45046016    // int[576]
#define OFF_NPOS  45048320    // int
#define OFF_TREG  45048336    // float[512]
#define OFF_TASKS 45050384    // int[1280]

// anchor w/h table; U = sqrt(128*128/2); power-of-2 multiples are exact in fp32.
#define UANC 90.509667991878f
__device__ __constant__ float WKa[9] = {128.0f, 2.0f*UANC, UANC, 256.0f, 4.0f*UANC, 2.0f*UANC, 512.0f, 8.0f*UANC, 4.0f*UANC};
__device__ __constant__ float HKa[9] = {128.0f, UANC, 2.0f*UANC, 256.0f, 2.0f*UANC, 4.0f*UANC, 512.0f, 4.0f*UANC, 8.0f*UANC};

__device__ __forceinline__ float iou_one(float x1, float y1, float x2, float y2, float4 t) {
#pragma clang fp contract(off)
  float ltx = fmaxf(t.x, x1), lty = fmaxf(t.y, y1);
  float rbx = fminf(t.z, x2), rby = fminf(t.w, y2);
  float wx = fmaxf(rbx - ltx, 0.0f);
  float wy = fmaxf(rby - lty, 0.0f);
  float inter = wx * wy;
  float at = (t.z - t.x) * (t.w - t.y);
  float aa = (x2 - x1) * (y2 - y1);
  return inter / ((at + aa) - inter);
}

__device__ __forceinline__ unsigned short f2bf(float f) {
  unsigned int u = __float_as_uint(f);
  unsigned int r = (u + 0x7fffu + ((u >> 16) & 1u)) >> 16;
  return (unsigned short)r;
}

// B-gather K-step offset (shorts): kcb in [0,576), 4-aligned, quad never carries into kc>>6
__device__ __forceinline__ int boff(int kcb) {
  int rk = kcb >> 6;                 // 0..8
  int dy = (rk * 11) >> 5;           // rk/3 for rk in [0,8]
  int dxo = rk - dy * 3;
  return (dy * 130 + dxo) * 512 + (kcb & 63) * 8;
}

// four-role kernel, all selection-independent work:
//   [0,576):      IoU + per-block candidate/zero stats
//   [576,2624):   x NCHW fp32 -> padded NHWC bf16 transpose (64x64 LDS tile)
//   [2624,3136):  weight repack, LDS-staged
//   [3136,3333):  zero page + halo zero-fill + out[0]=0
__global__ __launch_bounds__(256) void k_pi(const float* __restrict__ cw,
    unsigned short* __restrict__ Wb2, const float* __restrict__ x,
    unsigned short* __restrict__ xtb, unsigned short* __restrict__ zrg,
    const float* __restrict__ tgt, const int* __restrict__ imw,
    const int* __restrict__ imh, float* __restrict__ miou,
    ull* __restrict__ cand, int* __restrict__ cpb, int* __restrict__ cbz,
    float* __restrict__ out0) {
  __shared__ __align__(16) char smem[20480];
  int blk = blockIdx.x;
  int tid = threadIdx.x;
  if (blk >= NIOUB + NTRB + NPREP2) {          // ---- zero page + halo ----
    int g = (blk - (NIOUB + NTRB + NPREP2)) * 256 + tid;   // [0, 50432)
    uint4 z = {0u, 0u, 0u, 0u};
    if (g == 0) *out0 = 0.0f;                  // loss accumulator init
    if (g < 17408) {
      *(uint4*)(zrg + g * 8) = z;
    } else {
      int h = g - 17408;
      int pixi = h >> 6, j = h & 63;           // 516 halo pixels x 64 uint4
      int yy, xx;
      if (pixi < 260) { yy = (pixi < 130) ? 0 : 129; xx = (pixi < 130) ? pixi : pixi - 130; }
      else { int p2 = pixi - 260; if (p2 < 128) { yy = 1 + p2; xx = 0; } else { yy = p2 - 127; xx = 129; } }
      *(uint4*)(xtb + (size_t)(yy * 130 + xx) * 512 + j * 8) = z;
    }
    return;
  }
  if (blk >= NIOUB + NTRB) {                   // ---- prep: one cout row, LDS-staged ----
    float* row = (float*)smem;                 // padded [cin*10 + r]
    int m = blk - (NIOUB + NTRB);
    const float* src = cw + (size_t)m * KDIM;
    for (int f = tid; f < KDIM; f += 256) {
      int cin = f / 9;
      row[cin * 10 + (f - cin * 9)] = src[f];
    }
    __syncthreads();
    for (int kc = tid; kc < 576; kc += 256) {
      int r = kc >> 6, c8 = kc & 63;
      int base = c8 * 80 + r;
      unsigned short o[8];
      #pragma unroll
      for (int j = 0; j < 8; ++j) o[j] = f2bf(row[base + j * 10]);
      *(uint4*)(Wb2 + ((size_t)kc * 512 + m) * 8) = *(const uint4*)o;
    }
    return;
  }
  if (blk >= NIOUB) {                          // ---- transpose 64pix x 64cin, padded bf16 out ----
    float* tile = (float*)smem;                // [64][65]
    int tb = blk - NIOUB;
    int pix0 = (tb & 255) * 64;
    int cin0 = (tb >> 8) * 64;
    int pr = tid & 15, cr = tid >> 4;
    #pragma unroll
    for (int i = 0; i < 4; ++i) {
      int cin = cr + i * 16;
      float4 v = *(const float4*)(x + (size_t)(cin0 + cin) * 16384 + pix0 + pr * 4);
      tile[cin * 65 + pr * 4 + 0] = v.x;
      tile[cin * 65 + pr * 4 + 1] = v.y;
      tile[cin * 65 + pr * 4 + 2] = v.z;
      tile[cin * 65 + pr * 4 + 3] = v.w;
    }
    __syncthreads();
    // write: 16B stores, 8 bf16 along cin per lane; bank = (8*pr8+pix+j)%32 -> 2-way (free)
    int pr8 = tid & 7, cr8 = tid >> 3;         // 8 cin-groups x 32 pix rows
    #pragma unroll
    for (int pass = 0; pass < 2; ++pass) {
      int pix = cr8 + pass * 32;
      int plin = pix0 + pix;
      int py = plin >> 7, px = plin & 127;
      unsigned short o[8];
      #pragma unroll
      for (int j = 0; j < 8; ++j) o[j] = f2bf(tile[(pr8 * 8 + j) * 65 + pix]);
      *(uint4*)(xtb + (size_t)((py + 1) * 130 + (px + 1)) * 512 + cin0 + pr8 * 8) = *(const uint4*)o;
    }
    return;
  }
  // ---- IoU ----
  float4* ts = (float4*)smem;                  // [64]
  int* wz = (int*)(smem + 1024);
  int* wc = wz + 4;
  if (tid < NT) ts[tid] = ((const float4*)tgt)[tid];
  __syncthreads();
  int a = blk * 256 + tid;
  int k = a % 9;
  int pq = a / 9;
  int p = pq >> 7, q = pq & 127;
  float dx = (float)(*imw) / 127.0f;
  float dyl = (float)(*imh) / 127.0f;
  float x1 = (float)p * dx, y1 = (float)q * dyl;
  float x2 = x1 + WKa[k], y2 = y1 + HKa[k];
  float best = -1.0f;
  #pragma unroll 8
  for (int t = 0; t < NT; ++t) best = fmaxf(best, iou_one(x1, y1, x2, y2, ts[t]));
  miou[a] = best;
  int lane = tid & 63, w = tid >> 6;
  ull bz = __ballot(best == 0.0f);
  bool isc = best > 0.7f;
  ull bc = __ballot(isc);
  if (lane == 0) { wz[w] = (int)__popcll(bz); wc[w] = (int)__popcll(bc); }
  __syncthreads();
  if (tid == 0) {
    cbz[blk] = wz[0] + wz[1] + wz[2] + wz[3];
    cpb[blk] = wc[0] + wc[1] + wc[2] + wc[3];
  }
  if (isc) {
    int woff = 0;
    for (int i = 0; i < w; ++i) woff += wc[i];
    int rank = woff + (int)__popcll(bc & ((1ull << lane) - 1ull));
    cand[blk * 256 + rank] = ((ull)__float_as_uint(best) << 32) | (ull)(0xFFFFFFFFu - (unsigned)a);
  }
}

// two concurrent blocks:
//   block 0: pos-select (radix top-128 SET) + treg + pos task table [0,768)
//   block 1: neg-select + neg task table [768,1280) (recs unconditional;
//            np-validity is applied in k_out, which reads nposp anyway)
__global__ __launch_bounds__(256) void k_sel(const ull* __restrict__ cand,
    const int* __restrict__ cpb, const float* __restrict__ miou,
    const int* __restrict__ cbz, const float* __restrict__ tgt,
    const int* __restrict__ imw, const int* __restrict__ imh,
    int* __restrict__ nposp, float* __restrict__ treg, int* __restrict__ tasks) {
  __shared__ ull keys[CAND_CAP];               // 32 KB
  __shared__ ull bnd[1024];                    // 8 KB
  __shared__ int hist[1024];                   // 4 KB
  __shared__ int cpbL[576];
  __shared__ int base576[577];
  __shared__ int wtot[4];
  __shared__ int selCnt, bndCnt, Tbin, mAbove;
  __shared__ int posi[128];
  __shared__ int npS;
  __shared__ int nzbase[145];
  __shared__ float4 ts[NT];
  __shared__ int negA[256];
  __shared__ int wsum[4];
  int tid = threadIdx.x;
  int lane = tid & 63;

  if (blockIdx.x == 1) {                       // ======== neg path ========
    int sB = 0, scanB = 0;
    if (tid < 144) {
      int4 cz4 = *(const int4*)(cbz + 4 * tid);
      sB = cz4.x + cz4.y + cz4.z + cz4.w;
      scanB = sB;
      for (int off = 1; off < 64; off <<= 1) {
        int v = __shfl_up(scanB, off);
        if (lane >= off) scanB += v;
      }
      bool last = (tid < 128) ? (lane == 63) : (tid == 143);
      if (last) wsum[tid >> 6] = scanB;
    }
    __syncthreads();
    if (tid < 144) {
      int w = tid >> 6;
      int woff = 0;
      for (int i = 0; i < w; ++i) woff += wsum[i];
      nzbase[tid] = woff + scanB - sB;
      if (tid == 143) nzbase[144] = woff + scanB;
    }
    __syncthreads();
    int w = tid >> 6;
    for (int j = 0; j < 144; ++j) {
      if (nzbase[j] >= 256) break;             // uniform
      int a0 = j * 1024 + tid * 4;
      float4 m4 = *(const float4*)(miou + a0);
      int f0 = (m4.x == 0.0f), f1 = (m4.y == 0.0f), f2 = (m4.z == 0.0f), f3 = (m4.w == 0.0f);
      int tsum = f0 + f1 + f2 + f3;
      int scan = tsum;
      for (int off = 1; off < 64; off <<= 1) {
        int v = __shfl_up(scan, off);
        if (lane >= off) scan += v;
      }
      if (lane == 63) wsum[w] = scan;
      __syncthreads();
      int woff = nzbase[j];
      for (int i = 0; i < w; ++i) woff += wsum[i];
      int r = woff + scan - tsum;
      if (f0) { if (r < 256) negA[r] = a0;     r++; }
      if (f1) { if (r < 256) negA[r] = a0 + 1; r++; }
      if (f2) { if (r < 256) negA[r] = a0 + 2; r++; }
      if (f3) { if (r < 256) negA[r] = a0 + 3;      }
      __syncthreads();
    }
    __syncthreads();
    for (int t = 768 + tid; t < NTASK; t += 256) {
      int s = (t - 768) >> 1, jj = (t - 768) & 1;
      int a = negA[s];
      int f = 2 * a; int wr = 36 + (f >> 14); int yy = (f >> 7) & 127; int xx = (f & 127) + jj;
      tasks[t] = (int)(0x80000000u | ((unsigned)wr << 16) | ((unsigned)yy << 8) | (unsigned)xx);
    }
    return;
  }

  // ======== pos path (block 0) ========
  if (tid < NT) ts[tid] = ((const float4*)tgt)[tid];
  for (int i = tid; i < 576; i += 256) cpbL[i] = cpb[i];
  for (int i = tid; i < 1024; i += 256) hist[i] = 0;
  __syncthreads();
  int e0 = 0, e1 = 0, sA = 0, scanA = 0;
  if (tid < 192) {
    e0 = cpbL[3 * tid]; e1 = cpbL[3 * tid + 1]; int e2 = cpbL[3 * tid + 2];
    sA = e0 + e1 + e2;
    scanA = sA;
    for (int off = 1; off < 64; off <<= 1) {
      int v = __shfl_up(scanA, off);
      if (lane >= off) scanA += v;
    }
    if (lane == 63) wtot[tid >> 6] = scanA;
  }
  __syncthreads();
  if (tid < 192) {
    int w = tid >> 6;
    int woff = 0;
    for (int i = 0; i < w; ++i) woff += wtot[i];
    int excl = woff + scanA - sA;
    base576[3 * tid]     = excl;
    base576[3 * tid + 1] = excl + e0;
    base576[3 * tid + 2] = excl + e0 + e1;
    if (tid == 191) base576[576] = excl + sA;
  }
  __syncthreads();
  int cnt = base576[576]; if (cnt > CAND_CAP) cnt = CAND_CAP;
  for (int i = tid; i < CAND_CAP; i += 256) if (i >= cnt) keys[i] = 0ull;
  for (int rk = tid; rk < cnt; rk += 256) {
    int lo = 0, hi = 576;
    while (hi - lo > 1) { int mid = (lo + hi) >> 1; if (base576[mid] <= rk) lo = mid; else hi = mid; }
    keys[rk] = cand[lo * 256 + (rk - base576[lo])];
  }
  __syncthreads();
  if (cnt <= 128) {                            // set-invariant: slot order irrelevant
    if (tid < cnt) posi[tid] = (int)(0xFFFFFFFFu - (unsigned)(keys[tid] & 0xFFFFFFFFull));
    if (tid == 0) { npS = cnt; *nposp = cnt; }
  } else {
    for (int i = tid; i < cnt; i += 256) {
      unsigned ib = (unsigned)(keys[i] >> 32);
      atomicAdd(&hist[(ib - 0x3F333334u) >> 13], 1);
    }
    __syncthreads();
    if (tid < 64) {
      int s = 0;
      #pragma unroll
      for (int t = 0; t < 16; ++t) s += hist[tid * 16 + t];
      int S = s;
      #pragma unroll
      for (int off = 1; off < 64; off <<= 1) {
        int u = __shfl_down(S, off);
        if (tid + off < 64) S += u;
      }
      ull mask = __ballot(S >= 128);
      int g = 63 - __clzll(mask);
      int aboveS = __shfl(S, (g + 1 < 64) ? g + 1 : 63);
      if (g == 63) aboveS = 0;
      if (tid == 0) {
        int run = aboveS, T = g * 16 + 15;
        for (int b = g * 16 + 15; b >= g * 16; --b) {
          int h = hist[b];
          if (run + h >= 128) { T = b; break; }
          run += h;
        }
        Tbin = T; mAbove = run; selCnt = 0; bndCnt = 0;
      }
    }
    __syncthreads();
    int T = Tbin, m = mAbove;
    for (int i = tid; i < cnt; i += 256) {
      ull kk = keys[i];
      unsigned ib = (unsigned)(kk >> 32);
      int b = (int)((ib - 0x3F333334u) >> 13);
      if (b > T) {
        int r = atomicAdd(&selCnt, 1);
        posi[r] = (int)(0xFFFFFFFFu - (unsigned)(kk & 0xFFFFFFFFull));
      } else if (b == T) {
        int r = atomicAdd(&bndCnt, 1);
        if (r < 1024) bnd[r] = kk;
      }
    }
    __syncthreads();
    int B = bndCnt;
    int need = 128 - m;
    if (B <= 1024) {
      int n2 = 2; while (n2 < B) n2 <<= 1;
      for (int i = tid; i < n2; i += 256) if (i >= B) bnd[i] = 0ull;
      for (int size = 2; size <= n2; size <<= 1)
        for (int stride = size >> 1; stride > 0; stride >>= 1) {
          __syncthreads();
          for (int t = tid; t < n2 / 2; t += 256) {
            int i = 2 * t - (t & (stride - 1));
            int j = i + stride;
            ull a = bnd[i], b2 = bnd[j];
            bool desc = ((i & size) == 0);
            if (desc ? (a < b2) : (a > b2)) { bnd[i] = b2; bnd[j] = a; }
          }
        }
      __syncthreads();
      if (tid < need) posi[m + tid] = (int)(0xFFFFFFFFu - (unsigned)(bnd[tid] & 0xFFFFFFFFull));
    } else {                                   // pathological tie storm: full sort fallback
      for (int size = 2; size <= CAND_CAP; size <<= 1)
        for (int stride = size >> 1; stride > 0; stride >>= 1) {
          __syncthreads();
          for (int t = tid; t < CAND_CAP / 2; t += 256) {
            int i = 2 * t - (t & (stride - 1));
            int j = i + stride;
            ull a = keys[i], b2 = keys[j];
            bool desc = ((i & size) == 0);
            if (desc ? (a < b2) : (a > b2)) { keys[i] = b2; keys[j] = a; }
          }
        }
      __syncthreads();
      if (tid < 128) posi[tid] = (int)(0xFFFFFFFFu - (unsigned)(keys[tid] & 0xFFFFFFFFull));
    }
    if (tid == 0) { npS = 128; *nposp = 128; }
  }
  __syncthreads();
  int np = npS;
  if (tid < np) {
    int a = posi[tid];
    int k = a % 9; int pq = a / 9; int p = pq >> 7, q = pq & 127;
    float dx = (float)(*imw) / 127.0f, dyl = (float)(*imh) / 127.0f;
    float x1 = (float)p * dx, y1 = (float)q * dyl;
    float x2 = x1 + WKa[k], y2 = y1 + HKa[k];
    float best = -1.0f; int bt = 0;
    for (int t = 0; t < NT; ++t) {
      float v = iou_one(x1, y1, x2, y2, ts[t]);
      if (v > best) { best = v; bt = t; }      // first-max == jnp.argmax
    }
    float4 m = ts[bt];
    float aw = x2 - x1, ah = y2 - y1;
    float acx = x1 + aw * 0.5f, acy = y1 + ah * 0.5f;
    float bwd = m.z - m.x, bhd = m.w - m.y;
    float bcx = m.x + bwd * 0.5f, bcy = m.y + bhd * 0.5f;
    treg[tid * 4 + 0] = (bcx - acx) / aw;
    treg[tid * 4 + 1] = (bcy - acy) / ah;
    treg[tid * 4 + 2] = logf(bwd / aw);
    treg[tid * 4 + 3] = logf(bhd / ah);
  }
  for (int t = tid; t < 768; t += 256) {
    int rec = 0;
    int s = t / 6, jj = t - s * 6;
    if (s < np) {
      int a = posi[s];
      int f, wr, xx;
      if (jj < 4) { f = 4 * a; wr = f >> 14; xx = (f & 127) + jj; }
      else        { f = 2 * a; wr = 36 + (f >> 14); xx = (f & 127) + (jj - 4); }
      int yy = (f >> 7) & 127;
      rec = (int)(0x80000000u | ((unsigned)wr << 16) | ((unsigned)yy << 8) | (unsigned)xx);
    }
    tasks[t] = rec;
  }
}

// LDS-free bf16 MFMA GEMM, im2col folded into the B-operand gather.
// 1-wave blocks, 64x64 output tile. 1-D grid 1280 with XCD-aware decode:
// under round-robin XCD = i%8, XCD k owns K-slice k entirely -> its working
// set (8 A panels + 20 B tiles = 2.0 MB) is L2-resident; consecutive blocks
// on an XCD sweep m at fixed tt0 (B tile reused 8x back-to-back).
__global__ __launch_bounds__(64) void k_mfma(const unsigned short* __restrict__ Wb2,
    const unsigned short* __restrict__ xtb, const unsigned short* __restrict__ zrg,
    const int* __restrict__ tasks, const int* __restrict__ nposp,
    float* __restrict__ H4) {
  int i = blockIdx.x;                          // 0..1279
  int ks = i & 7;                              // XCD id under round-robin = K slice
  int m_base = ((i >> 3) & 7) * 64;            // m tile (fast within XCD)
  int tt0 = (i >> 6) * 64;                     // task tile
  int npos = *nposp;
  int posend = 6 * npos, negend = 768 + 2 * (256 - npos);
  if (!((tt0 < posend) || ((tt0 + 64 > 768) && (tt0 < negend)))) return;
  int lane = threadIdx.x;                      // 0..63
  int quad = lane >> 4, r = lane & 15;
  int kc0 = ks * 72 + quad;
  const bf16x8* Ab = (const bf16x8*)Wb2 + ((size_t)kc0 * 512 + m_base + r);

  // per-lane B gather base pointers (one task per (ni,r))
  const unsigned short* Bp[4];
  #pragma unroll
  for (int ni = 0; ni < 4; ++ni) {
    int rec = tasks[tt0 + ni * 16 + r];
    int pix = (rec < 0) ? (((rec >> 8) & 127) * 130 + (rec & 127)) : 0;
    const unsigned short* base = (rec < 0) ? xtb : zrg;
    Bp[ni] = base + (size_t)pix * 512 + quad * 8;
  }
  int kcb = ks * 72;

  f32x4 acc[4][4];
  #pragma unroll
  for (int ii = 0; ii < 4; ++ii)
    #pragma unroll
    for (int j = 0; j < 4; ++j) acc[ii][j] = (f32x4){0.f, 0.f, 0.f, 0.f};

  bf16x8 a[4], b[4];
  #pragma unroll
  for (int mi = 0; mi < 4; ++mi) a[mi] = Ab[mi * 16];
  int ob0 = boff(kcb);
  #pragma unroll
  for (int ni = 0; ni < 4; ++ni) b[ni] = *(const bf16x8*)(Bp[ni] + ob0);

  for (int s = 0; s < NSTEP; ++s) {
    bf16x8 an[4], bn[4];
    if (s < NSTEP - 1) {
      const bf16x8* An = Ab + (size_t)(s + 1) * 4 * 512;
      int ob = boff(kcb + 4 * (s + 1));
      #pragma unroll
      for (int mi = 0; mi < 4; ++mi) an[mi] = An[mi * 16];
      #pragma unroll
      for (int ni = 0; ni < 4; ++ni) bn[ni] = *(const bf16x8*)(Bp[ni] + ob);
    }
    #pragma unroll
    for (int mi = 0; mi < 4; ++mi)
      #pragma unroll
      for (int ni = 0; ni < 4; ++ni)
        acc[mi][ni] = __builtin_amdgcn_mfma_f32_16x16x32_bf16(a[mi], b[ni], acc[mi][ni], 0, 0, 0);
    if (s < NSTEP - 1) {
      #pragma unroll
      for (int mi = 0; mi < 4; ++mi) a[mi] = an[mi];
      #pragma unroll
      for (int ni = 0; ni < 4; ++ni) b[ni] = bn[ni];
    }
  }
  size_t hb = (size_t)ks * NTASK;
  #pragma unroll
  for (int mi = 0; mi < 4; ++mi) {
    int c = m_base + mi * 16 + quad * 4;
    #pragma unroll
    for (int ni = 0; ni < 4; ++ni) {
      int t = tt0 + ni * 16 + r;
      *(f32x4*)(H4 + (hb + t) * 512 + c) = acc[mi][ni];
    }
  }
}

// epilogue + loss: 4 tasks per block (wave per task); each block atomicAdds its
// pre-scaled CE/reg contributions directly into out[0] (zeroed by k_pi).
// CE pairs (t0,t0+1) never cross a 4-task block: t0 mod 4 is always even.
// Neg-task validity (s < 256-np) is applied HERE (neg recs are unconditional).
__global__ __launch_bounds__(256) void k_out(const float* __restrict__ H4,
    const int* __restrict__ tasks,
    const float* __restrict__ cb, const float* __restrict__ bw,
    const float* __restrict__ bb, const float* __restrict__ sw,
    const float* __restrict__ sb, const float* __restrict__ treg,
    const int* __restrict__ nposp, float* __restrict__ out) {
  __shared__ float sOut[4];
  __shared__ float sContrib[4];
  int wave = threadIdx.x >> 6, lane = threadIdx.x & 63;
  int t = blockIdx.x * 4 + wave;
  int rec = tasks[t];
  int np = *nposp;
  float outval = 0.0f;
  if (rec < 0) {
    int wr = (rec >> 16) & 63;
    const float* wrow = (wr < 36) ? (bw + wr * 512) : (sw + (wr - 36) * 512);
    float s = 0.0f;
    #pragma unroll
    for (int it = 0; it < 8; ++it) {
      int c = it * 64 + lane;
      size_t o = (size_t)t * 512 + c;
      float hv = cb[c];
      #pragma unroll
      for (int kslice = 0; kslice < KSPLIT; ++kslice)
        hv += H4[o + (size_t)kslice * 1280 * 512];
      s = fmaf(fmaxf(hv, 0.0f), wrow[c], s);
    }
    #pragma unroll
    for (int off = 32; off > 0; off >>= 1) s += __shfl_down(s, off);
    if (lane == 0) {
      float b = (wr < 36) ? bb[wr] : sb[wr - 36];
      outval = fmaxf(s + b, 0.0f);
    }
  }
  if (lane == 0) sOut[wave] = outval;
  __syncthreads();
  if (lane == 0) {
    float contrib = 0.0f;
    if (rec < 0) {
      if (t < 768) {
        int s6 = t / 6, j = t - s6 * 6;
        if (j < 4) {                           // smooth-L1 reg term
          float d = outval - treg[s6 * 4 + j];
          float ad = fabsf(d);
          float sl1 = (ad < 1.0f) ? 0.5f * d * d : ad - 0.5f;
          contrib = 10.0f * sl1 / fmaxf(4.0f * (float)np, 1.0f);
        } else if (j == 4) {                   // pos CE (partner j==5 at wave+1)
          float s0 = outval, s1 = sOut[wave + 1];
          float mm = fmaxf(s0, s1);
          float lse = mm + logf(expf(s0 - mm) + expf(s1 - mm));
          contrib = (lse - s0) * (1.0f / 256.0f);
        }
      } else if (((t - 768) & 1) == 0 && ((t - 768) >> 1) < 256 - np) {  // neg CE, masked by np
        float s0 = outval, s1 = sOut[wave + 1];
        float mm = fmaxf(s0, s1);
        float lse = mm + logf(expf(s0 - mm) + expf(s1 - mm));
        contrib = (lse - s1) * (1.0f / 256.0f);
      }
    }
    sContrib[wave] = contrib;
  }
  __syncthreads();
  if (threadIdx.x == 0) {
    float c = sContrib[0] + sContrib[1] + sContrib[2] + sContrib[3];
    if (c != 0.0f) atomicAdd(out, c);
  }
}

extern "C" void kernel_launch(void* const* d_in, const int* in_sizes, int n_in,
                              void* d_out, int out_size, void* d_ws, size_t ws_size,
                              hipStream_t stream) {
  const float* x   = (const float*)d_in[0];
  const float* tgt = (const float*)d_in[1];
  const float* cw  = (const float*)d_in[2];
  const float* cb  = (const float*)d_in[3];
  const float* bw  = (const float*)d_in[4];
  const float* bb  = (const float*)d_in[5];
  const float* sw  = (const float*)d_in[6];
  const float* sb  = (const float*)d_in[7];
  const int* imh   = (const int*)d_in[8];
  const int* imw   = (const int*)d_in[9];

  char* ws = (char*)d_ws;
  unsigned short* Wb2 = (unsigned short*)(ws + OFF_WB2);
  unsigned short* xtb = (unsigned short*)(ws + OFF_XT);
  unsigned short* zrg = (unsigned short*)(ws + OFF_ZERO);
  float* H4    = (float*)(ws + OFF_H4);
  float* miou  = (float*)(ws + OFF_MIOU);
  ull*   cand  = (ull*)(ws + OFF_CAND);
  int*   cpb   = (int*)(ws + OFF_CPB);
  int*   cbz   = (int*)(ws + OFF_CBZ);
  int*   nposp = (int*)(ws + OFF_NPOS);
  float* treg  = (float*)(ws + OFF_TREG);
  int*   tasks = (int*)(ws + OFF_TASKS);
  float* out   = (float*)d_out;

  k_pi   <<<dim3(NIOUB + NTRB + NPREP2 + NZERO), dim3(256), 0, stream>>>(cw, Wb2, x, xtb, zrg, tgt, imw, imh, miou, cand, cpb, cbz, out);
  k_sel  <<<dim3(2),              dim3(256), 0, stream>>>(cand, cpb, miou, cbz, tgt, imw, imh, nposp, treg, tasks);
  k_mfma <<<dim3(1280),           dim3(64),  0, stream>>>(Wb2, xtb, zrg, tasks, nposp, H4);
  k_out  <<<dim3(320),            dim3(256), 0, stream>>>(H4, tasks, cb, bw, bb, sw, sb, treg, nposp, out);
}